// Round 2
// baseline (170.202 us; speedup 1.0000x reference)
//
#include <hip/hip_runtime.h>

// MHA block: qkv proj -> flash attention -> out proj.  B=4,N=2048,DIM=512,H=8,Dh=64.
// All matmuls via mfma_f32_16x16x32_bf16 (verified m92/m97 fragment mapping):
//   A-frag: lane holds A[m=base+(lane&15)][k=(lane>>4)*8+b]
//   B-frag: lane holds B[n=base+(lane&15)][k=(lane>>4)*8+b]
//   C/D  : lane holds C[m=base+(lane>>4)*4+r][n=base+(lane&15)]
// V is written TRANSPOSED (Vt[feature][token]) by the QKV-GEMM epilogue so the
// attention PV B-operand is a plain contiguous global load (no tr-reads).

typedef __bf16 bf16x8 __attribute__((ext_vector_type(8)));
typedef float f32x4 __attribute__((ext_vector_type(4)));
typedef unsigned int u32;
typedef unsigned short u16;
typedef u32 u32x2v __attribute__((ext_vector_type(2)));
typedef u32 u32x4v __attribute__((ext_vector_type(4)));

__device__ __forceinline__ u16 f2bf(float f) {
  union { float f; u32 u; } v; v.f = f;
  u32 r = v.u + 0x7FFFu + ((v.u >> 16) & 1u);   // RNE
  return (u16)(r >> 16);
}

__device__ __forceinline__ f32x4 mfma16(bf16x8 a, bf16x8 b, f32x4 c) {
  return __builtin_amdgcn_mfma_f32_16x16x32_bf16(a, b, c, 0, 0, 0);
}

// ---------------- convert f32 -> bf16 ----------------
// x: 1048576 float4, w_qkv: 196608, w_out: 65536  (total 1310720 = 5120*256)
__global__ void convert_all(const float4* __restrict__ x, const float4* __restrict__ wq,
                            const float4* __restrict__ wo, u16* __restrict__ xb,
                            u16* __restrict__ wqb, u16* __restrict__ wob) {
  int t = blockIdx.x * blockDim.x + threadIdx.x;
  float4 v; u16* dst;
  if (t < 1048576)        { v = x[t];             dst = xb  + (size_t)t * 4; }
  else if (t < 1245184)   { int u = t - 1048576; v = wq[u]; dst = wqb + (size_t)u * 4; }
  else                    { int u = t - 1245184; v = wo[u]; dst = wob + (size_t)u * 4; }
  u32x2v o2;
  o2[0] = (u32)f2bf(v.x) | ((u32)f2bf(v.y) << 16);
  o2[1] = (u32)f2bf(v.z) | ((u32)f2bf(v.w) << 16);
  *(u32x2v*)dst = o2;
}

// ---------------- NT GEMM: C[m,n] = sum_k A[m,k]*B[n,k] ----------------
// 128x128 tile, BK=64, 4 waves (2x2), each wave 64x64 = 4x4 fragments.
// MODE 0 (QKV proj): cols <1024 -> bf16 row-major Cb; cols >=1024 (the V part)
//                    -> TRANSPOSED bf16 to Vt[col-1024][row]  (packed 8B stores).
// MODE 1 (out proj): f32 Cf + bias.
template<int MODE>
__global__ __launch_bounds__(256, 2) void gemm_nt(
    const u16* __restrict__ A, const u16* __restrict__ B,
    float* __restrict__ Cf, u16* __restrict__ Cb, u16* __restrict__ Vt,
    const float* __restrict__ bias, int M, int N, int K)
{
  __shared__ __align__(16) u16 As[128 * 64];
  __shared__ __align__(16) u16 Bs[128 * 64];
  const int tid = threadIdx.x;
  const int w = tid >> 6, lane = tid & 63, g = lane >> 4, c = lane & 15;
  const int wr = w >> 1, wc = w & 1;
  const long m0 = (long)blockIdx.y * 128;
  const long n0 = (long)blockIdx.x * 128;
  const f32x4 zero4 = {0.f, 0.f, 0.f, 0.f};

  f32x4 acc[4][4];
#pragma unroll
  for (int i = 0; i < 4; ++i)
#pragma unroll
    for (int j = 0; j < 4; ++j) acc[i][j] = zero4;

  const int srow = tid >> 3;            // 0..31
  const int sch  = (tid & 7) * 8;       // elem offset in row

#pragma unroll 1
  for (int kk = 0; kk < K; kk += 64) {
#pragma unroll
    for (int i = 0; i < 4; ++i) {
      __builtin_amdgcn_global_load_lds(
          (__attribute__((address_space(1))) void*)(A + (m0 + i * 32 + srow) * K + kk + sch),
          (__attribute__((address_space(3))) void*)(As + (i * 32 + w * 8) * 64),
          16, 0, 0);
      __builtin_amdgcn_global_load_lds(
          (__attribute__((address_space(1))) void*)(B + (n0 + i * 32 + srow) * K + kk + sch),
          (__attribute__((address_space(3))) void*)(Bs + (i * 32 + w * 8) * 64),
          16, 0, 0);
    }
    __syncthreads();   // drains vmcnt (global_load_lds) + lgkm

#pragma unroll
    for (int ks = 0; ks < 2; ++ks) {
      bf16x8 af[4], bfr[4];
#pragma unroll
      for (int mi = 0; mi < 4; ++mi)
        af[mi] = *(const bf16x8*)&As[(wr * 64 + mi * 16 + c) * 64 + ks * 32 + g * 8];
#pragma unroll
      for (int nj = 0; nj < 4; ++nj)
        bfr[nj] = *(const bf16x8*)&Bs[(wc * 64 + nj * 16 + c) * 64 + ks * 32 + g * 8];
#pragma unroll
      for (int mi = 0; mi < 4; ++mi)
#pragma unroll
        for (int nj = 0; nj < 4; ++nj)
          acc[mi][nj] = mfma16(af[mi], bfr[nj], acc[mi][nj]);
    }
    __syncthreads();
  }

  // epilogue: D row=(lane>>4)*4+r, col=lane&15
#pragma unroll
  for (int mi = 0; mi < 4; ++mi)
#pragma unroll
    for (int nj = 0; nj < 4; ++nj) {
      const long rowb = m0 + wr * 64 + mi * 16 + g * 4;
      const long col  = n0 + wc * 64 + nj * 16 + c;
      if (MODE == 1) {
#pragma unroll
        for (int r = 0; r < 4; ++r)
          Cf[(rowb + r) * N + col] = acc[mi][nj][r] + bias[col];
      } else if (n0 < 1024) {
#pragma unroll
        for (int r = 0; r < 4; ++r)
          Cb[(rowb + r) * N + col] = f2bf(acc[mi][nj][r]);
      } else {
        // transposed V store: Vt[col-1024][token], r=0..3 are consecutive tokens
        u32x2v pk;
        pk[0] = (u32)f2bf(acc[mi][nj][0]) | ((u32)f2bf(acc[mi][nj][1]) << 16);
        pk[1] = (u32)f2bf(acc[mi][nj][2]) | ((u32)f2bf(acc[mi][nj][3]) << 16);
        *(u32x2v*)&Vt[(col - 1024) * 8192 + rowb] = pk;
      }
    }
}

// ---------------- flash attention ----------------
// grid = B*H*16 blocks; block = 4 waves; wave owns 32 q rows; KV tile = 64.
// K staged in padded LDS (stride 72 elems = 144B, 16B-aligned rows).
// V^T read directly from global (Vt), P round-trips per-wave padded LDS.
__global__ __launch_bounds__(256, 2) void attn_fwd(const u16* __restrict__ qkv,
                                                   const u16* __restrict__ Vt,
                                                   u16* __restrict__ ao)
{
  __shared__ __align__(16) u16 Ks[64 * 72];
  __shared__ __align__(16) u16 Ps[4 * 32 * 72];  // per-wave P[32 q][64 kv] padded

  const int tid = threadIdx.x;
  const int w = tid >> 6, lane = tid & 63, g = lane >> 4, c = lane & 15;
  const int qb = blockIdx.x & 15;
  const int bh = blockIdx.x >> 4;
  const long rowbase = (long)(bh >> 3) * 2048;   // token base for this batch
  const int hcol = (bh & 7) * 64;                // feature base for this head
  const int q0 = qb * 128 + w * 32;
  const f32x4 zero4 = {0.f, 0.f, 0.f, 0.f};

  // Q A-frags: Q[q=q0+mi*16+c][d=ks*32+g*8+b]
  bf16x8 qf[2][2];
#pragma unroll
  for (int mi = 0; mi < 2; ++mi)
#pragma unroll
    for (int ks = 0; ks < 2; ++ks)
      qf[mi][ks] = *(const bf16x8*)(qkv + (rowbase + q0 + mi * 16 + c) * 1536 + hcol + ks * 32 + g * 8);

  float mrun[2][4], lrun[2][4];
  f32x4 o[2][4];
#pragma unroll
  for (int mi = 0; mi < 2; ++mi) {
#pragma unroll
    for (int r = 0; r < 4; ++r) { mrun[mi][r] = -1e30f; lrun[mi][r] = 0.f; }
#pragma unroll
    for (int n = 0; n < 4; ++n) o[mi][n] = zero4;
  }

  const u16* kbase = qkv + rowbase * 1536 + 512 + hcol;
  const u16* vtb   = Vt + (long)hcol * 8192 + rowbase;  // V^T[d][token] base
  const int sr = tid >> 2, sd = (tid & 3) * 16;
  u16* Pw = Ps + w * (32 * 72);

#pragma unroll 1
  for (int t = 0; t < 32; ++t) {
    const long kv0 = (long)t * 64;

    // V^T B-frags straight from global (issued early; latency hides under QK^T)
    bf16x8 bv[4][2];
#pragma unroll
    for (int n = 0; n < 4; ++n)
#pragma unroll
      for (int ks = 0; ks < 2; ++ks)
        bv[n][ks] = *(const bf16x8*)(vtb + (long)(n * 16 + c) * 8192 + kv0 + ks * 32 + g * 8);

    { // stage K tile (64 rows x 64 d), padded rows
      const u16* kg = kbase + (kv0 + sr) * 1536 + sd;
      u32x4v k1 = *(const u32x4v*)kg;
      u32x4v k2 = *(const u32x4v*)(kg + 8);
      *(u32x4v*)&Ks[sr * 72 + sd]     = k1;
      *(u32x4v*)&Ks[sr * 72 + sd + 8] = k2;
    }
    __syncthreads();

    // S = Q K^T : B-frag K[kv=n*16+c][d=ks*32+g*8+b]
    bf16x8 bk[4][2];
#pragma unroll
    for (int n = 0; n < 4; ++n)
#pragma unroll
      for (int ks = 0; ks < 2; ++ks)
        bk[n][ks] = *(const bf16x8*)&Ks[(n * 16 + c) * 72 + ks * 32 + g * 8];

    f32x4 s[2][4];
#pragma unroll
    for (int mi = 0; mi < 2; ++mi)
#pragma unroll
      for (int n = 0; n < 4; ++n) {
        f32x4 a0 = zero4;
        a0 = mfma16(qf[mi][0], bk[n][0], a0);
        a0 = mfma16(qf[mi][1], bk[n][1], a0);
        s[mi][n] = a0 * 0.125f;   // DIM_HEAD^-0.5
      }

    // online softmax: q-row = mi*16 + g*4 + r lives in the 16 lanes sharing g
    float alpha_v[2][4];
#pragma unroll
    for (int mi = 0; mi < 2; ++mi)
#pragma unroll
      for (int r = 0; r < 4; ++r) {
        float v = fmaxf(fmaxf(s[mi][0][r], s[mi][1][r]), fmaxf(s[mi][2][r], s[mi][3][r]));
        v = fmaxf(v, __shfl_xor(v, 1));
        v = fmaxf(v, __shfl_xor(v, 2));
        v = fmaxf(v, __shfl_xor(v, 4));
        v = fmaxf(v, __shfl_xor(v, 8));
        float mold = mrun[mi][r];
        float mnew = fmaxf(mold, v);
        float a = __expf(mold - mnew);
        mrun[mi][r] = mnew;
        lrun[mi][r] *= a;
        alpha_v[mi][r] = a;
      }
#pragma unroll
    for (int mi = 0; mi < 2; ++mi) {
      f32x4 av = {alpha_v[mi][0], alpha_v[mi][1], alpha_v[mi][2], alpha_v[mi][3]};
#pragma unroll
      for (int n = 0; n < 4; ++n) o[mi][n] *= av;
    }

    float rs[2][4];
#pragma unroll
    for (int mi = 0; mi < 2; ++mi)
#pragma unroll
      for (int r = 0; r < 4; ++r) rs[mi][r] = 0.f;

    // p = exp(s-m); write P row-major to per-wave LDS (scalar b16 stores)
#pragma unroll
    for (int mi = 0; mi < 2; ++mi)
#pragma unroll
      for (int n = 0; n < 4; ++n) {
#pragma unroll
        for (int r = 0; r < 4; ++r) {
          float p = __expf(s[mi][n][r] - mrun[mi][r]);
          rs[mi][r] += p;
          Pw[(mi * 16 + g * 4 + r) * 72 + n * 16 + c] = f2bf(p);
        }
      }
#pragma unroll
    for (int mi = 0; mi < 2; ++mi)
#pragma unroll
      for (int r = 0; r < 4; ++r) {
        float t2 = rs[mi][r];
        t2 += __shfl_xor(t2, 1);
        t2 += __shfl_xor(t2, 2);
        t2 += __shfl_xor(t2, 4);
        t2 += __shfl_xor(t2, 8);
        lrun[mi][r] += t2;
      }

    // same-wave LDS write->read: force completion, then read A-frags
    asm volatile("s_waitcnt lgkmcnt(0)" ::: "memory");
    bf16x8 pa[2][2];
#pragma unroll
    for (int mi = 0; mi < 2; ++mi)
#pragma unroll
      for (int ks = 0; ks < 2; ++ks)
        pa[mi][ks] = *(const bf16x8*)&Pw[(mi * 16 + c) * 72 + ks * 32 + g * 8];

    // O += P V : A=P[q][kv], B=V^T[d][kv]
#pragma unroll
    for (int mi = 0; mi < 2; ++mi)
#pragma unroll
      for (int ks = 0; ks < 2; ++ks)
#pragma unroll
        for (int n = 0; n < 4; ++n)
          o[mi][n] = mfma16(pa[mi][ks], bv[n][ks], o[mi][n]);

    __syncthreads();   // protect Ks before next stage
  }

  // epilogue: AO[token][h*64+d]
#pragma unroll
  for (int mi = 0; mi < 2; ++mi)
#pragma unroll
    for (int n = 0; n < 4; ++n) {
      f32x4 ov = o[mi][n];
#pragma unroll
      for (int r = 0; r < 4; ++r) {
        long row = rowbase + q0 + mi * 16 + g * 4 + r;
        long col = hcol + n * 16 + c;
        ao[row * 512 + col] = f2bf(ov[r] / lrun[mi][r]);
      }
    }
}

extern "C" void kernel_launch(void* const* d_in, const int* in_sizes, int n_in,
                              void* d_out, int out_size, void* d_ws, size_t ws_size,
                              hipStream_t stream) {
  (void)in_sizes; (void)n_in; (void)out_size; (void)ws_size;
  const float* x    = (const float*)d_in[0];
  const float* wqkv = (const float*)d_in[1];
  const float* wout = (const float*)d_in[2];
  const float* bout = (const float*)d_in[3];

  char* ws = (char*)d_ws;
  // layout (MiB): Xb@0 (8), Wqb@8 (1.5), Wob@9.5 (0.5), QKV@10 (24), Vt@34 (8).
  // AO aliases Xb (dead after gemm0; rewritten by convert each call).
  u16* Xb  = (u16*)(ws);
  u16* Wqb = (u16*)(ws + (8ull << 20));
  u16* Wob = (u16*)(ws + (9ull << 20) + (512ull << 10));
  u16* QKV = (u16*)(ws + (10ull << 20));
  u16* Vt  = (u16*)(ws + (34ull << 20));
  u16* AO  = (u16*)(ws);

  convert_all<<<5120, 256, 0, stream>>>((const float4*)x, (const float4*)wqkv,
                                        (const float4*)wout, Xb, Wqb, Wob);
  gemm_nt<0><<<dim3(12, 64), 256, 0, stream>>>(Xb, Wqb, nullptr, QKV, Vt, nullptr, 8192, 1536, 512);
  attn_fwd<<<512, 256, 0, stream>>>(QKV, Vt, AO);
  gemm_nt<1><<<dim3(4, 64), 256, 0, stream>>>(AO, Wob, (float*)d_out, nullptr, nullptr, bout, 8192, 512, 512);
}

// Round 4
// 158.330 us; speedup vs baseline: 1.0750x; 1.0750x over previous
//
#include <hip/hip_runtime.h>

// MHA block: qkv proj -> flash attention -> out proj.  B=4,N=2048,DIM=512,H=8,Dh=64.
// mfma_f32_16x16x32_bf16 fragment mapping (verified m92/m97):
//   A-frag: lane holds A[m=base+(lane&15)][k=(lane>>4)*8+b]
//   B-frag: lane holds B[n=base+(lane&15)][k=(lane>>4)*8+b]
//   C/D  : lane holds C[m=base+(lane>>4)*4+r][n=base+(lane&15)]
// V is written TRANSPOSED (Vt[feature][token]) by the QKV-GEMM epilogue; attn
// stages the Vt tile through padded LDS with coalesced row loads (tokens are
// the contiguous dim), then reads B-frags like K.  K/V tiles are prefetched
// into registers one tile ahead (latency hides under compute).

typedef __bf16 bf16x8 __attribute__((ext_vector_type(8)));
typedef float f32x4 __attribute__((ext_vector_type(4)));
typedef unsigned int u32;
typedef unsigned short u16;
typedef u32 u32x2v __attribute__((ext_vector_type(2)));
typedef u32 u32x4v __attribute__((ext_vector_type(4)));

__device__ __forceinline__ u16 f2bf(float f) {
  union { float f; u32 u; } v; v.f = f;
  u32 r = v.u + 0x7FFFu + ((v.u >> 16) & 1u);   // RNE
  return (u16)(r >> 16);
}

__device__ __forceinline__ f32x4 mfma16(bf16x8 a, bf16x8 b, f32x4 c) {
  return __builtin_amdgcn_mfma_f32_16x16x32_bf16(a, b, c, 0, 0, 0);
}

// ---------------- convert f32 -> bf16 ----------------
__global__ void convert_all(const float4* __restrict__ x, const float4* __restrict__ wq,
                            const float4* __restrict__ wo, u16* __restrict__ xb,
                            u16* __restrict__ wqb, u16* __restrict__ wob) {
  int t = blockIdx.x * blockDim.x + threadIdx.x;
  float4 v; u16* dst;
  if (t < 1048576)        { v = x[t];             dst = xb  + (size_t)t * 4; }
  else if (t < 1245184)   { int u = t - 1048576; v = wq[u]; dst = wqb + (size_t)u * 4; }
  else                    { int u = t - 1245184; v = wo[u]; dst = wob + (size_t)u * 4; }
  u32x2v o2;
  o2[0] = (u32)f2bf(v.x) | ((u32)f2bf(v.y) << 16);
  o2[1] = (u32)f2bf(v.z) | ((u32)f2bf(v.w) << 16);
  *(u32x2v*)dst = o2;
}

// ---------------- NT GEMM: C[m,n] = sum_k A[m,k]*B[n,k] ----------------
// 128x128 tile, BK=64, 4 waves (2x2), each wave 64x64 = 4x4 fragments.
// MODE 0 (QKV proj): cols <1024 -> bf16 row-major Cb; cols >=1024 (V part)
//                    -> TRANSPOSED bf16 to Vt[col-1024][row] (packed 8B stores).
// MODE 1 (out proj): f32 Cf + bias.
template<int MODE>
__global__ __launch_bounds__(256, 2) void gemm_nt(
    const u16* __restrict__ A, const u16* __restrict__ B,
    float* __restrict__ Cf, u16* __restrict__ Cb, u16* __restrict__ Vt,
    const float* __restrict__ bias, int M, int N, int K)
{
  __shared__ __align__(16) u16 As[128 * 64];
  __shared__ __align__(16) u16 Bs[128 * 64];
  const int tid = threadIdx.x;
  const int w = tid >> 6, lane = tid & 63, g = lane >> 4, c = lane & 15;
  const int wr = w >> 1, wc = w & 1;
  const long m0 = (long)blockIdx.y * 128;
  const long n0 = (long)blockIdx.x * 128;
  const f32x4 zero4 = {0.f, 0.f, 0.f, 0.f};

  f32x4 acc[4][4];
#pragma unroll
  for (int i = 0; i < 4; ++i)
#pragma unroll
    for (int j = 0; j < 4; ++j) acc[i][j] = zero4;

  const int srow = tid >> 3;            // 0..31
  const int sch  = (tid & 7) * 8;       // elem offset in row

#pragma unroll 1
  for (int kk = 0; kk < K; kk += 64) {
#pragma unroll
    for (int i = 0; i < 4; ++i) {
      __builtin_amdgcn_global_load_lds(
          (__attribute__((address_space(1))) void*)(A + (m0 + i * 32 + srow) * K + kk + sch),
          (__attribute__((address_space(3))) void*)(As + (i * 32 + w * 8) * 64),
          16, 0, 0);
      __builtin_amdgcn_global_load_lds(
          (__attribute__((address_space(1))) void*)(B + (n0 + i * 32 + srow) * K + kk + sch),
          (__attribute__((address_space(3))) void*)(Bs + (i * 32 + w * 8) * 64),
          16, 0, 0);
    }
    __syncthreads();

#pragma unroll
    for (int ks = 0; ks < 2; ++ks) {
      bf16x8 af[4], bfr[4];
#pragma unroll
      for (int mi = 0; mi < 4; ++mi)
        af[mi] = *(const bf16x8*)&As[(wr * 64 + mi * 16 + c) * 64 + ks * 32 + g * 8];
#pragma unroll
      for (int nj = 0; nj < 4; ++nj)
        bfr[nj] = *(const bf16x8*)&Bs[(wc * 64 + nj * 16 + c) * 64 + ks * 32 + g * 8];
#pragma unroll
      for (int mi = 0; mi < 4; ++mi)
#pragma unroll
        for (int nj = 0; nj < 4; ++nj)
          acc[mi][nj] = mfma16(af[mi], bfr[nj], acc[mi][nj]);
    }
    __syncthreads();
  }

  // epilogue: D row=(lane>>4)*4+r, col=lane&15
#pragma unroll
  for (int mi = 0; mi < 4; ++mi)
#pragma unroll
    for (int nj = 0; nj < 4; ++nj) {
      const long rowb = m0 + wr * 64 + mi * 16 + g * 4;
      const long col  = n0 + wc * 64 + nj * 16 + c;
      if (MODE == 1) {
#pragma unroll
        for (int r = 0; r < 4; ++r)
          Cf[(rowb + r) * N + col] = acc[mi][nj][r] + bias[col];
      } else if (n0 < 1024) {
#pragma unroll
        for (int r = 0; r < 4; ++r)
          Cb[(rowb + r) * N + col] = f2bf(acc[mi][nj][r]);
      } else {
        // transposed V store: Vt[col-1024][token], r=0..3 consecutive tokens
        u32x2v pk;
        pk[0] = (u32)f2bf(acc[mi][nj][0]) | ((u32)f2bf(acc[mi][nj][1]) << 16);
        pk[1] = (u32)f2bf(acc[mi][nj][2]) | ((u32)f2bf(acc[mi][nj][3]) << 16);
        *(u32x2v*)&Vt[(col - 1024) * 8192 + rowb] = pk;
      }
    }
}

// ---------------- flash attention ----------------
// grid = 1024 blocks (32 bh x 32 qb), 4 waves; wave owns 16 q rows; KV tile 64.
// K and V^T tiles staged in padded LDS (stride 72 elems = 144B, 16B-aligned),
// prefetched one tile ahead into registers.  P round-trips per-wave padded LDS.
__global__ __launch_bounds__(256, 4) void attn_fwd(const u16* __restrict__ qkv,
                                                   const u16* __restrict__ Vt,
                                                   u16* __restrict__ ao)
{
  __shared__ __align__(16) u16 Ks [64 * 72];
  __shared__ __align__(16) u16 Vts[64 * 72];
  __shared__ __align__(16) u16 Ps [4 * 16 * 72];  // per-wave P[16 q][64 kv] padded

  const int tid = threadIdx.x;
  const int w = tid >> 6, lane = tid & 63, g = lane >> 4, c = lane & 15;

  // bh-major XCD swizzle: XCD x gets bh in [4x, 4x+4)  (1024 % 8 == 0, bijective)
  const int swz = (blockIdx.x & 7) * 128 + (blockIdx.x >> 3);
  const int bh = swz >> 5;
  const int qb = swz & 31;
  const long rowbase = (long)(bh >> 3) * 2048;   // token base for this batch
  const int hcol = (bh & 7) * 64;                // feature base for this head
  const int q0 = qb * 64 + w * 16;
  const f32x4 zero4 = {0.f, 0.f, 0.f, 0.f};

  // Q A-frags: Q[q=q0+c][d=ks*32+g*8+b]
  bf16x8 qf[2];
#pragma unroll
  for (int ks = 0; ks < 2; ++ks)
    qf[ks] = *(const bf16x8*)(qkv + (rowbase + q0 + c) * 1536 + hcol + ks * 32 + g * 8);

  float mrun[4], lrun[4];
  f32x4 o[4];
#pragma unroll
  for (int r = 0; r < 4; ++r) { mrun[r] = -1e30f; lrun[r] = 0.f; }
#pragma unroll
  for (int n = 0; n < 4; ++n) o[n] = zero4;

  const u16* kbase = qkv + rowbase * 1536 + 512 + hcol;
  const u16* vtb   = Vt + (long)hcol * 8192 + rowbase;  // V^T[d][token] base
  const int sr = tid >> 2, sd = (tid & 3) * 16;
  u16* Pw = Ps + w * (16 * 72);

  // prefetch tile 0 into registers
  const u16* kg = kbase + (long)sr * 1536 + sd;
  const u16* vg = vtb + (long)sr * 8192 + sd;
  u32x4v kr0 = *(const u32x4v*)kg;
  u32x4v kr1 = *(const u32x4v*)(kg + 8);
  u32x4v vr0 = *(const u32x4v*)vg;
  u32x4v vr1 = *(const u32x4v*)(vg + 8);

#pragma unroll 1
  for (int t = 0; t < 32; ++t) {
    // write staged regs to LDS
    *(u32x4v*)&Ks [sr * 72 + sd]     = kr0;
    *(u32x4v*)&Ks [sr * 72 + sd + 8] = kr1;
    *(u32x4v*)&Vts[sr * 72 + sd]     = vr0;
    *(u32x4v*)&Vts[sr * 72 + sd + 8] = vr1;
    __syncthreads();

    // prefetch next tile (latency hides under this tile's compute)
    if (t < 31) {
      const long kv1 = (long)(t + 1) * 64;
      const u16* kg2 = kbase + (kv1 + sr) * 1536 + sd;
      const u16* vg2 = vtb + (long)sr * 8192 + kv1 + sd;
      kr0 = *(const u32x4v*)kg2;
      kr1 = *(const u32x4v*)(kg2 + 8);
      vr0 = *(const u32x4v*)vg2;
      vr1 = *(const u32x4v*)(vg2 + 8);
    }

    // S = Q K^T : B-frag K[kv=n*16+c][d=ks*32+g*8+b]
    bf16x8 bk[4][2];
#pragma unroll
    for (int n = 0; n < 4; ++n)
#pragma unroll
      for (int ks = 0; ks < 2; ++ks)
        bk[n][ks] = *(const bf16x8*)&Ks[(n * 16 + c) * 72 + ks * 32 + g * 8];

    f32x4 s[4];
#pragma unroll
    for (int n = 0; n < 4; ++n) {
      f32x4 a0 = zero4;
      a0 = mfma16(qf[0], bk[n][0], a0);
      a0 = mfma16(qf[1], bk[n][1], a0);
      s[n] = a0 * 0.125f;   // DIM_HEAD^-0.5
    }

    // V^T B-frags from LDS (issued before softmax; lgkm hides under VALU)
    bf16x8 bv[4][2];
#pragma unroll
    for (int n = 0; n < 4; ++n)
#pragma unroll
      for (int ks = 0; ks < 2; ++ks)
        bv[n][ks] = *(const bf16x8*)&Vts[(n * 16 + c) * 72 + ks * 32 + g * 8];

    // online softmax: q-row = g*4 + r lives in the 16 lanes sharing g
    float alpha_v[4];
#pragma unroll
    for (int r = 0; r < 4; ++r) {
      float v = fmaxf(fmaxf(s[0][r], s[1][r]), fmaxf(s[2][r], s[3][r]));
      v = fmaxf(v, __shfl_xor(v, 1));
      v = fmaxf(v, __shfl_xor(v, 2));
      v = fmaxf(v, __shfl_xor(v, 4));
      v = fmaxf(v, __shfl_xor(v, 8));
      float mold = mrun[r];
      float mnew = fmaxf(mold, v);
      float a = __expf(mold - mnew);
      mrun[r] = mnew;
      lrun[r] *= a;
      alpha_v[r] = a;
    }
    {
      f32x4 av = {alpha_v[0], alpha_v[1], alpha_v[2], alpha_v[3]};
#pragma unroll
      for (int n = 0; n < 4; ++n) o[n] *= av;
    }

    float rs[4] = {0.f, 0.f, 0.f, 0.f};
    // p = exp(s-m); write P row-major to per-wave LDS
#pragma unroll
    for (int n = 0; n < 4; ++n)
#pragma unroll
      for (int r = 0; r < 4; ++r) {
        float p = __expf(s[n][r] - mrun[r]);
        rs[r] += p;
        Pw[(g * 4 + r) * 72 + n * 16 + c] = f2bf(p);
      }
#pragma unroll
    for (int r = 0; r < 4; ++r) {
      float t2 = rs[r];
      t2 += __shfl_xor(t2, 1);
      t2 += __shfl_xor(t2, 2);
      t2 += __shfl_xor(t2, 4);
      t2 += __shfl_xor(t2, 8);
      lrun[r] += t2;
    }

    // same-wave LDS write->read: force completion, then read P A-frags
    asm volatile("s_waitcnt lgkmcnt(0)" ::: "memory");
    bf16x8 pa[2];
#pragma unroll
    for (int ks = 0; ks < 2; ++ks)
      pa[ks] = *(const bf16x8*)&Pw[c * 72 + ks * 32 + g * 8];

    // O += P V : A=P[q][kv], B=V^T[d][kv]
#pragma unroll
    for (int ks = 0; ks < 2; ++ks)
#pragma unroll
      for (int n = 0; n < 4; ++n)
        o[n] = mfma16(pa[ks], bv[n][ks], o[n]);

    __syncthreads();   // protect Ks/Vts before next stage
  }

  // epilogue: AO[token][h*64+d]
#pragma unroll
  for (int n = 0; n < 4; ++n) {
    f32x4 ov = o[n];
#pragma unroll
    for (int r = 0; r < 4; ++r) {
      long row = rowbase + q0 + g * 4 + r;
      long col = hcol + n * 16 + c;
      ao[row * 512 + col] = f2bf(ov[r] / lrun[r]);
    }
  }
}

extern "C" void kernel_launch(void* const* d_in, const int* in_sizes, int n_in,
                              void* d_out, int out_size, void* d_ws, size_t ws_size,
                              hipStream_t stream) {
  (void)in_sizes; (void)n_in; (void)out_size; (void)ws_size;
  const float* x    = (const float*)d_in[0];
  const float* wqkv = (const float*)d_in[1];
  const float* wout = (const float*)d_in[2];
  const float* bout = (const float*)d_in[3];

  char* ws = (char*)d_ws;
  // layout (MiB): Xb@0 (8), Wqb@8 (1.5), Wob@9.5 (0.5), QKV@10 (24), Vt@34 (8).
  // AO aliases Xb (dead after gemm0; rewritten by convert each call).
  u16* Xb  = (u16*)(ws);
  u16* Wqb = (u16*)(ws + (8ull << 20));
  u16* Wob = (u16*)(ws + (9ull << 20) + (512ull << 10));
  u16* QKV = (u16*)(ws + (10ull << 20));
  u16* Vt  = (u16*)(ws + (34ull << 20));
  u16* AO  = (u16*)(ws);

  convert_all<<<5120, 256, 0, stream>>>((const float4*)x, (const float4*)wqkv,
                                        (const float4*)wout, Xb, Wqb, Wob);
  gemm_nt<0><<<dim3(12, 64), 256, 0, stream>>>(Xb, Wqb, nullptr, QKV, Vt, nullptr, 8192, 1536, 512);
  attn_fwd<<<1024, 256, 0, stream>>>(QKV, Vt, AO);
  gemm_nt<1><<<dim3(4, 64), 256, 0, stream>>>(AO, Wob, (float*)d_out, nullptr, nullptr, bout, 8192, 512, 512);
}

// Round 5
// 122.369 us; speedup vs baseline: 1.3909x; 1.2939x over previous
//
#include <hip/hip_runtime.h>

// MHA block: qkv proj -> flash attention -> out proj.  B=4,N=2048,DIM=512,H=8,Dh=64.
// mfma_f32_16x16x32_bf16 fragment mapping (verified m92/m97):
//   A-frag (1st arg): lane holds A[m=base+(lane&15)][k=(lane>>4)*8+b]  -> output ROW
//   B-frag (2nd arg): lane holds B[n=base+(lane&15)][k=(lane>>4)*8+b]  -> output COL
//   C/D  : lane holds C[m=base+(lane>>4)*4+r][n=base+(lane&15)]
// attn uses SWAPPED operands: S^T = mfma(K,Q) so each lane owns one q-row
// (scalar m/l state, in-lane row reductions), and O^T = mfma(V^T, P).

typedef __bf16 bf16x8 __attribute__((ext_vector_type(8)));
typedef __bf16 bf16x4v __attribute__((ext_vector_type(4)));
typedef float f32x4 __attribute__((ext_vector_type(4)));
typedef unsigned int u32;
typedef unsigned short u16;
typedef u32 u32x2v __attribute__((ext_vector_type(2)));
typedef u32 u32x4v __attribute__((ext_vector_type(4)));

__device__ __forceinline__ u16 f2bf(float f) {
  union { float f; u32 u; } v; v.f = f;
  u32 r = v.u + 0x7FFFu + ((v.u >> 16) & 1u);   // RNE
  return (u16)(r >> 16);
}

// 4x f32 -> packed bf16x4 (compiler emits v_cvt_pk_bf16_f32 pairs)
__device__ __forceinline__ u32x2v pack4bf(float a, float b, float c, float d) {
  bf16x4v v; v[0] = (__bf16)a; v[1] = (__bf16)b; v[2] = (__bf16)c; v[3] = (__bf16)d;
  return __builtin_bit_cast(u32x2v, v);
}

__device__ __forceinline__ f32x4 mfma16(bf16x8 a, bf16x8 b, f32x4 c) {
  return __builtin_amdgcn_mfma_f32_16x16x32_bf16(a, b, c, 0, 0, 0);
}

// ---------------- convert f32 -> bf16 ----------------
__global__ void convert_all(const float4* __restrict__ x, const float4* __restrict__ wq,
                            const float4* __restrict__ wo, u16* __restrict__ xb,
                            u16* __restrict__ wqb, u16* __restrict__ wob) {
  int t = blockIdx.x * blockDim.x + threadIdx.x;
  float4 v; u16* dst;
  if (t < 1048576)        { v = x[t];             dst = xb  + (size_t)t * 4; }
  else if (t < 1245184)   { int u = t - 1048576; v = wq[u]; dst = wqb + (size_t)u * 4; }
  else                    { int u = t - 1245184; v = wo[u]; dst = wob + (size_t)u * 4; }
  u32x2v o2;
  o2[0] = (u32)f2bf(v.x) | ((u32)f2bf(v.y) << 16);
  o2[1] = (u32)f2bf(v.z) | ((u32)f2bf(v.w) << 16);
  *(u32x2v*)dst = o2;
}

// ---------------- NT GEMM: C[m,n] = sum_k A[m,k]*B[n,k] ----------------
// 128x128 tile, BK=64, 4 waves (2x2), each wave 64x64 = 4x4 fragments.
// MODE 0 (QKV proj): cols <1024 -> bf16 row-major Cb; cols >=1024 (V part)
//                    -> TRANSPOSED bf16 to Vt[col-1024][row] (packed 8B stores).
// MODE 1 (out proj): f32 Cf + bias.
template<int MODE>
__global__ __launch_bounds__(256, 2) void gemm_nt(
    const u16* __restrict__ A, const u16* __restrict__ B,
    float* __restrict__ Cf, u16* __restrict__ Cb, u16* __restrict__ Vt,
    const float* __restrict__ bias, int M, int N, int K)
{
  __shared__ __align__(16) u16 As[128 * 64];
  __shared__ __align__(16) u16 Bs[128 * 64];
  const int tid = threadIdx.x;
  const int w = tid >> 6, lane = tid & 63, g = lane >> 4, c = lane & 15;
  const int wr = w >> 1, wc = w & 1;
  const long m0 = (long)blockIdx.y * 128;
  const long n0 = (long)blockIdx.x * 128;
  const f32x4 zero4 = {0.f, 0.f, 0.f, 0.f};

  f32x4 acc[4][4];
#pragma unroll
  for (int i = 0; i < 4; ++i)
#pragma unroll
    for (int j = 0; j < 4; ++j) acc[i][j] = zero4;

  const int srow = tid >> 3;            // 0..31
  const int sch  = (tid & 7) * 8;       // elem offset in row

#pragma unroll 1
  for (int kk = 0; kk < K; kk += 64) {
#pragma unroll
    for (int i = 0; i < 4; ++i) {
      __builtin_amdgcn_global_load_lds(
          (__attribute__((address_space(1))) void*)(A + (m0 + i * 32 + srow) * K + kk + sch),
          (__attribute__((address_space(3))) void*)(As + (i * 32 + w * 8) * 64),
          16, 0, 0);
      __builtin_amdgcn_global_load_lds(
          (__attribute__((address_space(1))) void*)(B + (n0 + i * 32 + srow) * K + kk + sch),
          (__attribute__((address_space(3))) void*)(Bs + (i * 32 + w * 8) * 64),
          16, 0, 0);
    }
    __syncthreads();

#pragma unroll
    for (int ks = 0; ks < 2; ++ks) {
      bf16x8 af[4], bfr[4];
#pragma unroll
      for (int mi = 0; mi < 4; ++mi)
        af[mi] = *(const bf16x8*)&As[(wr * 64 + mi * 16 + c) * 64 + ks * 32 + g * 8];
#pragma unroll
      for (int nj = 0; nj < 4; ++nj)
        bfr[nj] = *(const bf16x8*)&Bs[(wc * 64 + nj * 16 + c) * 64 + ks * 32 + g * 8];
#pragma unroll
      for (int mi = 0; mi < 4; ++mi)
#pragma unroll
        for (int nj = 0; nj < 4; ++nj)
          acc[mi][nj] = mfma16(af[mi], bfr[nj], acc[mi][nj]);
    }
    __syncthreads();
  }

  // epilogue: D row=(lane>>4)*4+r, col=lane&15
#pragma unroll
  for (int mi = 0; mi < 4; ++mi)
#pragma unroll
    for (int nj = 0; nj < 4; ++nj) {
      const long rowb = m0 + wr * 64 + mi * 16 + g * 4;
      const long col  = n0 + wc * 64 + nj * 16 + c;
      if (MODE == 1) {
#pragma unroll
        for (int r = 0; r < 4; ++r)
          Cf[(rowb + r) * N + col] = acc[mi][nj][r] + bias[col];
      } else if (n0 < 1024) {
#pragma unroll
        for (int r = 0; r < 4; ++r)
          Cb[(rowb + r) * N + col] = f2bf(acc[mi][nj][r]);
      } else {
        // transposed V store: Vt[col-1024][token], r=0..3 consecutive tokens
        u32x2v pk;
        pk[0] = (u32)f2bf(acc[mi][nj][0]) | ((u32)f2bf(acc[mi][nj][1]) << 16);
        pk[1] = (u32)f2bf(acc[mi][nj][2]) | ((u32)f2bf(acc[mi][nj][3]) << 16);
        *(u32x2v*)&Vt[(col - 1024) * 8192 + rowb] = pk;
      }
    }
}

// ---------------- flash attention (swapped-operand form) ----------------
// grid = 1024 blocks (32 bh x 32 qb), 4 waves; wave owns 16 q rows; KV tile 64.
// S^T = mfma(K,Q): lane (g,c) holds S[q=c][kv=n*16+g*4+r] -> q-row is lane-local:
// scalar m/l, in-lane row reduce + 2 shfl.  P packed 4-wide -> 4 ds_write_b64,
// read back as B-frag (2 ds_read_b128).  O^T = mfma(V^T, P) -> packed stores.
__global__ __launch_bounds__(256, 4) void attn_fwd(const u16* __restrict__ qkv,
                                                   const u16* __restrict__ Vt,
                                                   u16* __restrict__ ao)
{
  __shared__ __align__(16) u16 Ks [64 * 72];
  __shared__ __align__(16) u16 Vts[64 * 72];
  __shared__ __align__(16) u16 Ps [4 * 16 * 72];  // per-wave P[16 q][64 kv] padded

  const int tid = threadIdx.x;
  const int w = tid >> 6, lane = tid & 63, g = lane >> 4, c = lane & 15;

  // bh-major XCD swizzle (1024 % 8 == 0, bijective)
  const int swz = (blockIdx.x & 7) * 128 + (blockIdx.x >> 3);
  const int bh = swz >> 5;
  const int qb = swz & 31;
  const long rowbase = (long)(bh >> 3) * 2048;   // token base for this batch
  const int hcol = (bh & 7) * 64;                // feature base for this head
  const int q0 = qb * 64 + w * 16;
  const f32x4 zero4 = {0.f, 0.f, 0.f, 0.f};
  const float SC = 0.18033688f;                  // 0.125 * log2(e)

  // Q B-frags: Q[q=q0+c][d=ks*32+g*8+b]
  bf16x8 qf[2];
#pragma unroll
  for (int ks = 0; ks < 2; ++ks)
    qf[ks] = *(const bf16x8*)(qkv + (rowbase + q0 + c) * 1536 + hcol + ks * 32 + g * 8);

  float mrun = -1e30f, lrun = 0.f;
  f32x4 o[4];
#pragma unroll
  for (int n = 0; n < 4; ++n) o[n] = zero4;

  const u16* kbase = qkv + rowbase * 1536 + 512 + hcol;
  const u16* vtb   = Vt + (long)hcol * 8192 + rowbase;  // V^T[d][token] base
  const int sr = tid >> 2, sd = (tid & 3) * 16;
  u16* Pw = Ps + w * (16 * 72);

  // prefetch tile 0 into registers
  const u16* kg = kbase + (long)sr * 1536 + sd;
  const u16* vg = vtb + (long)sr * 8192 + sd;
  u32x4v kr0 = *(const u32x4v*)kg;
  u32x4v kr1 = *(const u32x4v*)(kg + 8);
  u32x4v vr0 = *(const u32x4v*)vg;
  u32x4v vr1 = *(const u32x4v*)(vg + 8);

#pragma unroll 1
  for (int t = 0; t < 32; ++t) {
    // write staged regs to LDS
    *(u32x4v*)&Ks [sr * 72 + sd]     = kr0;
    *(u32x4v*)&Ks [sr * 72 + sd + 8] = kr1;
    *(u32x4v*)&Vts[sr * 72 + sd]     = vr0;
    *(u32x4v*)&Vts[sr * 72 + sd + 8] = vr1;
    __syncthreads();

    // prefetch next tile (latency hides under this tile's compute)
    if (t < 31) {
      const long kv1 = (long)(t + 1) * 64;
      const u16* kg2 = kbase + (kv1 + sr) * 1536 + sd;
      const u16* vg2 = vtb + (long)sr * 8192 + kv1 + sd;
      kr0 = *(const u32x4v*)kg2;
      kr1 = *(const u32x4v*)(kg2 + 8);
      vr0 = *(const u32x4v*)vg2;
      vr1 = *(const u32x4v*)(vg2 + 8);
    }

    // K A-frags: K[kv=n*16+c][d=ks*32+g*8+b]
    bf16x8 bk[4][2];
#pragma unroll
    for (int n = 0; n < 4; ++n)
#pragma unroll
      for (int ks = 0; ks < 2; ++ks)
        bk[n][ks] = *(const bf16x8*)&Ks[(n * 16 + c) * 72 + ks * 32 + g * 8];

    // S^T = K Q^T : lane (g,c) gets S[q=c][kv=n*16+g*4+r]  (raw, unscaled)
    f32x4 s[4];
#pragma unroll
    for (int n = 0; n < 4; ++n) {
      f32x4 a0 = zero4;
      a0 = mfma16(bk[n][0], qf[0], a0);
      a0 = mfma16(bk[n][1], qf[1], a0);
      s[n] = a0;
    }

    // V^T A-frags from LDS (issued before softmax; lgkm hides under VALU)
    bf16x8 bv[4][2];
#pragma unroll
    for (int n = 0; n < 4; ++n)
#pragma unroll
      for (int ks = 0; ks < 2; ++ks)
        bv[n][ks] = *(const bf16x8*)&Vts[(n * 16 + c) * 72 + ks * 32 + g * 8];

    // row max: in-lane tree over 16 + 2 cross-g shfl
    float pm;
    {
      f32x4 m4 = s[0];
      m4 = __builtin_elementwise_max(m4, s[1]);
      m4 = __builtin_elementwise_max(m4, s[2]);
      m4 = __builtin_elementwise_max(m4, s[3]);
      pm = fmaxf(fmaxf(m4[0], m4[1]), fmaxf(m4[2], m4[3]));
      pm = fmaxf(pm, __shfl_xor(pm, 16));
      pm = fmaxf(pm, __shfl_xor(pm, 32));
    }

    // defer-max (T13): rescale only when tile max grew past mrun+64 raw (=e^8)
    if (!__all(pm <= mrun + 64.0f)) {
      float mnew = fmaxf(mrun, pm);
      float alpha = exp2f((mrun - mnew) * SC);
      lrun *= alpha;
#pragma unroll
      for (int n = 0; n < 4; ++n) o[n] *= alpha;
      mrun = mnew;
    }
    const float msc = mrun * SC;

    // p = 2^(s*SC - msc); in-lane sum; pack 4 consecutive kv -> ds_write_b64
    float rowsum = 0.f;
#pragma unroll
    for (int n = 0; n < 4; ++n) {
      float p0 = exp2f(fmaf(s[n][0], SC, -msc));
      float p1 = exp2f(fmaf(s[n][1], SC, -msc));
      float p2 = exp2f(fmaf(s[n][2], SC, -msc));
      float p3 = exp2f(fmaf(s[n][3], SC, -msc));
      rowsum += (p0 + p1) + (p2 + p3);
      u32x2v pk = pack4bf(p0, p1, p2, p3);
      *(u32x2v*)&Pw[c * 72 + n * 16 + g * 4] = pk;
    }
    rowsum += __shfl_xor(rowsum, 16);
    rowsum += __shfl_xor(rowsum, 32);
    lrun += rowsum;

    // same-wave LDS write->read: force completion, then read P B-frags
    asm volatile("s_waitcnt lgkmcnt(0)" ::: "memory");
    bf16x8 pa[2];
#pragma unroll
    for (int ks = 0; ks < 2; ++ks)
      pa[ks] = *(const bf16x8*)&Pw[c * 72 + ks * 32 + g * 8];

    // O^T += V^T P^T : output row = d (from bv), col = q (from pa)
#pragma unroll
    for (int ks = 0; ks < 2; ++ks)
#pragma unroll
      for (int n = 0; n < 4; ++n)
        o[n] = mfma16(bv[n][ks], pa[ks], o[n]);

    __syncthreads();   // protect Ks/Vts before next stage
  }

  // epilogue: lane (g,c) holds O[q=q0+c][d=n*16+g*4+r] -> packed 8B stores
  const float linv = 1.0f / lrun;
  u16* aor = ao + (rowbase + q0 + c) * 512 + hcol;
#pragma unroll
  for (int n = 0; n < 4; ++n) {
    u32x2v pk = pack4bf(o[n][0] * linv, o[n][1] * linv, o[n][2] * linv, o[n][3] * linv);
    *(u32x2v*)&aor[n * 16 + g * 4] = pk;
  }
}

extern "C" void kernel_launch(void* const* d_in, const int* in_sizes, int n_in,
                              void* d_out, int out_size, void* d_ws, size_t ws_size,
                              hipStream_t stream) {
  (void)in_sizes; (void)n_in; (void)out_size; (void)ws_size;
  const float* x    = (const float*)d_in[0];
  const float* wqkv = (const float*)d_in[1];
  const float* wout = (const float*)d_in[2];
  const float* bout = (const float*)d_in[3];

  char* ws = (char*)d_ws;
  // layout (MiB): Xb@0 (8), Wqb@8 (1.5), Wob@9.5 (0.5), QKV@10 (24), Vt@34 (8).
  // AO aliases Xb (dead after gemm0; rewritten by convert each call).
  u16* Xb  = (u16*)(ws);
  u16* Wqb = (u16*)(ws + (8ull << 20));
  u16* Wob = (u16*)(ws + (9ull << 20) + (512ull << 10));
  u16* QKV = (u16*)(ws + (10ull << 20));
  u16* Vt  = (u16*)(ws + (34ull << 20));
  u16* AO  = (u16*)(ws);

  convert_all<<<5120, 256, 0, stream>>>((const float4*)x, (const float4*)wqkv,
                                        (const float4*)wout, Xb, Wqb, Wob);
  gemm_nt<0><<<dim3(12, 64), 256, 0, stream>>>(Xb, Wqb, nullptr, QKV, Vt, nullptr, 8192, 1536, 512);
  attn_fwd<<<1024, 256, 0, stream>>>(QKV, Vt, AO);
  gemm_nt<1><<<dim3(4, 64), 256, 0, stream>>>(AO, Wob, (float*)d_out, nullptr, nullptr, bout, 8192, 512, 512);
}